// Round 13
// baseline (210.439 us; speedup 1.0000x reference)
//
#include <hip/hip_runtime.h>
#include <hip/hip_bf16.h>

#define NNODES 100000
#define NEDGES 640000
#define DIM 128
#define GS 16
#define EB 128                                 // edges per block (1 per thread, 512 thr)
#define NSCAN_BLOCKS ((NNODES + 255) / 256)    // 391
#define G1_BLOCKS ((NNODES + 63) / 64)         // 1563 (tail block: 32 rows)
#define EDGE_BLOCKS (NEDGES / EB)              // 5000 (divisible by 8)

typedef __attribute__((ext_vector_type(8))) short short8;
typedef __attribute__((ext_vector_type(4))) float f32x4;
typedef __attribute__((ext_vector_type(2))) float f2;
typedef __attribute__((ext_vector_type(4))) unsigned int uint4v;

__device__ __forceinline__ ushort f2bf(float f) {
    __hip_bfloat16 h = __float2bfloat16(f);
    return *reinterpret_cast<ushort*>(&h);
}
__device__ __forceinline__ float bf2f(ushort u) {
    union { unsigned int i; float f; } v; v.i = ((unsigned int)u) << 16; return v.f;
}
__device__ __forceinline__ f2 sp(float x) { return (f2){x, x}; }

// ---------------------------------------------------------------- zero init + weight pack
__global__ void zero_kernel(float* __restrict__ out, int* __restrict__ hist,
                            int* __restrict__ cnt,
                            const float* __restrict__ W1, const float* __restrict__ W2,
                            ushort* __restrict__ w1p, ushort* __restrict__ w2p) {
    long step = (long)gridDim.x * blockDim.x;
    long i0 = (long)blockIdx.x * blockDim.x + threadIdx.x;
    const long total = (long)NNODES * DIM;
    for (long i = i0; i < total; i += step) out[i] = 0.f;
    for (long i = i0; i < NNODES; i += step) { hist[i] = 0; cnt[i] = 0; }
    // weight pre-pack (first 49152 threads)
    int idx = (int)i0;
    if (idx < 32768) {
        int j    = idx & 7;
        int lane = (idx >> 3) & 63;
        int kt   = (idx >> 9) & 3;
        int nt   = (idx >> 11) & 3;
        int w    = (idx >> 13) & 3;
        int lr = lane & 15, lg = lane >> 4;
        int koff = (w >= 2) ? 128 : 0;
        int cc = (w & 1) * 64 + nt * 16 + lr;
        int kb = koff + kt * 32 + lg * 8;
        w1p[idx] = f2bf(W1[(long)(kb + j) * DIM + cc]);
    } else if (idx < 49152) {
        int i2 = idx - 32768;   // < 16384
        int j    = i2 & 7;
        int lane = (i2 >> 3) & 63;
        int kt   = (i2 >> 9) & 3;
        int nt   = (i2 >> 11) & 1;
        int w    = (i2 >> 12) & 3;
        int lr = lane & 15, lg = lane >> 4;
        int cc = w * 32 + nt * 16 + lr;
        int kb = kt * 32 + lg * 8;
        w2p[i2] = f2bf(W2[(long)(kb + j) * DIM + cc]);
    }
}

// ---------------------------------------------------------------- node GEMM1 (MFMA)
// xab[n][0:128] = x@W1a + b1 (b1 folded),  xab[n][128:256] = x@W1b   (bf16)
__global__ __launch_bounds__(256) void node_gemm1(const float* __restrict__ x,
                                                  const ushort* __restrict__ w1p,
                                                  const float* __restrict__ b1,
                                                  ushort* __restrict__ xab) {
    __shared__ __align__(16) char xt[64 * 256];   // 64 rows x 128 bf16, XOR-swizzled
    const int tid  = threadIdx.x;
    const int lane = tid & 63;
    const int w    = tid >> 6;
    const int lr   = lane & 15;
    const int lg   = lane >> 4;
    const int m0   = blockIdx.x * 64;
    const int mtMax = (m0 + 64 <= NNODES) ? 4 : 2;
    const int koff = (w >= 2) ? 128 : 0;

    short8 bfrag[4][4];
    #pragma unroll
    for (int nt = 0; nt < 4; ++nt)
        #pragma unroll
        for (int kt = 0; kt < 4; ++kt)
            bfrag[nt][kt] = *(const short8*)&w1p[(((w * 4 + nt) * 4 + kt) << 9) + lane * 8];

    {
        const int r  = tid >> 2;
        const int kq = (tid & 3) * 32;
        if (m0 + r < NNODES) {
            const float* xr = &x[(long)(m0 + r) * DIM + kq];
            ushort tmp[32];
            #pragma unroll
            for (int j = 0; j < 32; ++j) tmp[j] = f2bf(xr[j]);
            #pragma unroll
            for (int i = 0; i < 4; ++i) {
                int byte = r * 256 + kq * 2 + i * 16;
                byte ^= (r & 7) << 4;
                *(short8*)(xt + byte) = *(short8*)&tmp[i * 8];
            }
        }
    }
    __syncthreads();

    const int colBase = w * 64;
    for (int mt = 0; mt < mtMax; ++mt) {
        short8 afrag[4];
        #pragma unroll
        for (int kt = 0; kt < 4; ++kt) {
            const int row = mt * 16 + lr;
            int byte = row * 256 + (kt * 4 + lg) * 16;
            byte ^= (row & 7) << 4;
            afrag[kt] = *(short8*)(xt + byte);
        }
        f32x4 acc[4] = {};
        #pragma unroll
        for (int nt = 0; nt < 4; ++nt)
            #pragma unroll
            for (int kt = 0; kt < 4; ++kt)
                acc[nt] = __builtin_amdgcn_mfma_f32_16x16x32_bf16(afrag[kt], bfrag[nt][kt], acc[nt], 0, 0, 0);
        #pragma unroll
        for (int nt = 0; nt < 4; ++nt) {
            const int col = colBase + nt * 16 + lr;
            const float badd = (koff == 0) ? b1[col] : 0.f;
            #pragma unroll
            for (int r = 0; r < 4; ++r) {
                const int row = m0 + mt * 16 + lg * 4 + r;
                xab[(long)row * 256 + col] = f2bf(acc[nt][r] + badd);
            }
        }
    }
}

// ---------------------------------------------------------------- histogram
__global__ void hist_kernel(const int* __restrict__ ei, int* __restrict__ hist) {
    int e = blockIdx.x * 256 + threadIdx.x;
    if (e < NEDGES) atomicAdd(&hist[ei[NEDGES + e]], 1);
}

// ---------------------------------------------------------------- 2-level scan
__global__ void scan1_kernel(const int* __restrict__ hist, int* __restrict__ excl,
                             int* __restrict__ bsums) {
    __shared__ int s[256];
    int tid = threadIdx.x;
    int i = blockIdx.x * 256 + tid;
    int v = (i < NNODES) ? hist[i] : 0;
    s[tid] = v;
    __syncthreads();
    for (int o = 1; o < 256; o <<= 1) {
        int t = (tid >= o) ? s[tid - o] : 0;
        __syncthreads();
        s[tid] += t;
        __syncthreads();
    }
    if (i < NNODES) excl[i] = s[tid] - v;
    if (tid == 255) bsums[blockIdx.x] = s[255];
}

__global__ void scan2_kernel(int* __restrict__ bsums) {
    __shared__ int s[512];
    int tid = threadIdx.x;
    int v = (tid < NSCAN_BLOCKS) ? bsums[tid] : 0;
    s[tid] = v;
    __syncthreads();
    for (int o = 1; o < 512; o <<= 1) {
        int t = (tid >= o) ? s[tid - o] : 0;
        __syncthreads();
        s[tid] += t;
        __syncthreads();
    }
    if (tid < NSCAN_BLOCKS) bsums[tid] = s[tid] - v;   // exclusive
}

// ---------------------------------------------------------------- scatter (counting sort)
__global__ void scatter_kernel(const int* __restrict__ ei, const float* __restrict__ ea,
                               const int* __restrict__ excl, const int* __restrict__ bsums,
                               int* __restrict__ cnt,
                               int2* __restrict__ dstsrc, float4* __restrict__ eas) {
    int e = blockIdx.x * 256 + threadIdx.x;
    if (e < NEDGES) {
        int d = ei[NEDGES + e];
        int pos = excl[d] + bsums[d >> 8] + atomicAdd(&cnt[d], 1);
        dstsrc[pos] = make_int2(d, ei[e]);
        eas[pos] = *(const float4*)&ea[(long)e * 4];
    }
}

// ---------------------------------------------------------------- edge phase
// 512 threads, 128 edges/block; XCD-chunked swizzle; pair-packed math;
// bf16 swizzled LDS; 4x32-edge segmented walk -> merged atomics
__global__ __launch_bounds__(512) void edge_silu_kernel(
    const ushort* __restrict__ xab,
    const int2* __restrict__ dstsrc, const float4* __restrict__ eas,
    const float* __restrict__ W1,
    const float* __restrict__ gamma, const float* __restrict__ beta,
    float* __restrict__ out)
{
    __shared__ __align__(16) ushort ssilu[EB * 128];   // 32 KB bf16, XOR-swizzled rows
    __shared__ __align__(16) float4 wA[68];            // skew p = pi + (pi>>4)
    __shared__ __align__(16) float4 wB[68];
    __shared__ __align__(16) float4 gbp[68];
    __shared__ int2   sds[EB];
    __shared__ float4 sea4[EB];

    const int tid = threadIdx.x;
    // XCD-chunked bijective swizzle: 5000 blocks = 8 XCDs x 625
    const int bid = (blockIdx.x & 7) * (EDGE_BLOCKS / 8) + (blockIdx.x >> 3);
    const int e0 = bid * EB;

    if (tid < EB) {
        sds[tid]  = dstsrc[e0 + tid];
        sea4[tid] = eas[e0 + tid];
    }
    if (tid < 64) {
        int pi = tid;
        int c0 = 2 * pi;
        int p = pi + (pi >> 4);
        wA[p]  = make_float4(W1[256 * DIM + c0], W1[256 * DIM + c0 + 1],
                             W1[257 * DIM + c0], W1[257 * DIM + c0 + 1]);
        wB[p]  = make_float4(W1[258 * DIM + c0], W1[258 * DIM + c0 + 1],
                             W1[259 * DIM + c0], W1[259 * DIM + c0 + 1]);
        gbp[p] = make_float4(gamma[c0], gamma[c0 + 1], beta[c0], beta[c0 + 1]);
    }
    __syncthreads();

    // h-phase: thread owns edge e = tid>>2, channel pairs [q*16, q*16+16)
    {
        const int e = tid >> 2;
        const int q = tid & 3;
        const int c0 = q * 32;
        const int2 ds = sds[e];
        const uint* xaRow = (const uint*)&xab[(long)ds.x * 256 + c0];
        const uint* xbRow = (const uint*)&xab[(long)ds.y * 256 + 128 + c0];
        const float4 a = sea4[e];

        uint4v ua[4], ub[4];
        #pragma unroll
        for (int i = 0; i < 4; ++i) {
            ua[i] = *(const uint4v*)&xaRow[i * 4];
            ub[i] = *(const uint4v*)&xbRow[i * 4];
        }

        f2 v2[16];
        #pragma unroll
        for (int k = 0; k < 16; ++k) {
            const int p = q * 16 + k + q;                 // skewed pair index
            const float4 a01 = wA[p];
            const float4 a23 = wB[p];
            f2 acc = (f2){a01.x, a01.y} * sp(a.x) + (f2){a01.z, a01.w} * sp(a.y)
                   + (f2){a23.x, a23.y} * sp(a.z) + (f2){a23.z, a23.w} * sp(a.w);
            const uint uga = ua[k >> 2][k & 3];
            const uint ugb = ub[k >> 2][k & 3];
            acc += (f2){__uint_as_float(uga << 16), __uint_as_float(uga & 0xffff0000u)};
            acc += (f2){__uint_as_float(ugb << 16), __uint_as_float(ugb & 0xffff0000u)};
            v2[k] = acc;
        }

        // GroupNorm (one-pass) + SiLU; thread owns 2 groups = 8 pairs each
        #pragma unroll
        for (int g = 0; g < 2; ++g) {
            f2 s = sp(0.f), ss = sp(0.f);
            #pragma unroll
            for (int ip = 0; ip < 8; ++ip) {
                f2 a2 = v2[g * 8 + ip];
                s += a2; ss += a2 * a2;
            }
            const float sum = s.x + s.y;
            const float sq  = ss.x + ss.y;
            const float m = sum * (1.f / GS);
            const float var = sq * (1.f / GS) - m * m;
            const float inv = __builtin_amdgcn_rsqf(var + 1e-5f);
            #pragma unroll
            for (int ip = 0; ip < 8; ++ip) {
                const int k = g * 8 + ip;
                const int p = q * 16 + k + q;
                const float4 gb4 = gbp[p];
                f2 sc  = (f2){gb4.x, gb4.y} * sp(inv);
                f2 off = (f2){gb4.z, gb4.w} - sc * sp(m);
                f2 t = v2[k] * sc + off;
                f2 r;
                r.x = t.x * __builtin_amdgcn_rcpf(1.f + __expf(-t.x));
                r.y = t.y * __builtin_amdgcn_rcpf(1.f + __expf(-t.y));
                v2[k] = r;
            }
        }

        // store silu as bf16, proven row-XOR swizzle
        ushort tmp[32];
        #pragma unroll
        for (int k = 0; k < 16; ++k) { tmp[2 * k] = f2bf(v2[k].x); tmp[2 * k + 1] = f2bf(v2[k].y); }
        #pragma unroll
        for (int i = 0; i < 4; ++i) {
            int byte = (e * 256 + (c0 + i * 8) * 2) ^ ((e & 7) << 4);
            *(short8*)((char*)ssilu + byte) = *(short8*)&tmp[i * 8];
        }
    }
    __syncthreads();

    // segmented column-walk: thread = (channel c = tid&127, segment tid>>7 of 32 edges)
    {
        const int c = tid & 127;
        const int h = tid >> 7;
        const int eS = h * 32, eE = eS + 32;
        float r = 0.f;
        int cur = sds[eS].x;
        for (int ee = eS; ee < eE; ++ee) {
            int d = sds[ee].x;
            if (d != cur) {
                unsafeAtomicAdd(&out[(long)cur * DIM + c], r);
                r = 0.f; cur = d;
            }
            int byte = (ee * 256 + c * 2) ^ ((ee & 7) << 4);
            r += bf2f(*(const ushort*)((const char*)ssilu + byte));
        }
        unsafeAtomicAdd(&out[(long)cur * DIM + c], r);
    }
}

// ---------------------------------------------------------------- node GEMM2 (MFMA, in-place)
__global__ __launch_bounds__(256) void node_gemm2(float* __restrict__ out,
                                                  const ushort* __restrict__ w2p,
                                                  const float* __restrict__ b2,
                                                  const int* __restrict__ hist) {
    __shared__ __align__(16) char at[64 * 256];
    __shared__ float sb2[128];
    __shared__ int scnt[64];
    const int tid  = threadIdx.x;
    const int lane = tid & 63;
    const int w    = tid >> 6;
    const int lr   = lane & 15;
    const int lg   = lane >> 4;
    const int m0   = blockIdx.x * 64;
    const int mtMax = (m0 + 64 <= NNODES) ? 4 : 2;

    short8 bfrag[2][4];
    #pragma unroll
    for (int nt = 0; nt < 2; ++nt)
        #pragma unroll
        for (int kt = 0; kt < 4; ++kt)
            bfrag[nt][kt] = *(const short8*)&w2p[(((w * 2 + nt) * 4 + kt) << 9) + lane * 8];

    if (tid < 128) sb2[tid] = b2[tid];
    if (tid < 64 && m0 + tid < NNODES) scnt[tid] = hist[m0 + tid];

    {
        const int r  = tid >> 2;
        const int kq = (tid & 3) * 32;
        if (m0 + r < NNODES) {
            const float* ar = &out[(long)(m0 + r) * DIM + kq];
            ushort tmp[32];
            #pragma unroll
            for (int j = 0; j < 32; ++j) tmp[j] = f2bf(ar[j]);
            #pragma unroll
            for (int i = 0; i < 4; ++i) {
                int byte = r * 256 + kq * 2 + i * 16;
                byte ^= (r & 7) << 4;
                *(short8*)(at + byte) = *(short8*)&tmp[i * 8];
            }
        }
    }
    __syncthreads();

    for (int mt = 0; mt < mtMax; ++mt) {
        short8 afrag[4];
        #pragma unroll
        for (int kt = 0; kt < 4; ++kt) {
            const int row = mt * 16 + lr;
            int byte = row * 256 + (kt * 4 + lg) * 16;
            byte ^= (row & 7) << 4;
            afrag[kt] = *(short8*)(at + byte);
        }
        f32x4 acc[2] = {};
        #pragma unroll
        for (int nt = 0; nt < 2; ++nt)
            #pragma unroll
            for (int kt = 0; kt < 4; ++kt)
                acc[nt] = __builtin_amdgcn_mfma_f32_16x16x32_bf16(afrag[kt], bfrag[nt][kt], acc[nt], 0, 0, 0);
        #pragma unroll
        for (int nt = 0; nt < 2; ++nt) {
            const int col = w * 32 + nt * 16 + lr;
            #pragma unroll
            for (int r = 0; r < 4; ++r) {
                const int rr = mt * 16 + lg * 4 + r;
                float cnt = (float)scnt[rr];
                float sc = __builtin_amdgcn_rcpf(fmaxf(cnt, 1.f));
                out[(long)(m0 + rr) * DIM + col] = (acc[nt][r] + cnt * sb2[col]) * sc;
            }
        }
    }
}

// ---------------------------------------------------------------- launch
extern "C" void kernel_launch(void* const* d_in, const int* in_sizes, int n_in,
                              void* d_out, int out_size, void* d_ws, size_t ws_size,
                              hipStream_t stream) {
    const float* x     = (const float*)d_in[0];
    const int*   ei    = (const int*)  d_in[1];
    const float* ea    = (const float*)d_in[2];
    const float* W1    = (const float*)d_in[3];
    const float* b1    = (const float*)d_in[4];
    const float* gamma = (const float*)d_in[5];
    const float* beta  = (const float*)d_in[6];
    const float* W2    = (const float*)d_in[7];
    const float* b2    = (const float*)d_in[8];
    float* out = (float*)d_out;

    char* ws = (char*)d_ws;
    size_t off = 0;
    ushort* xab   = (ushort*)(ws + off); off += (size_t)NNODES * 256 * sizeof(ushort);
    int*    hist  = (int*)   (ws + off); off += (size_t)NNODES * sizeof(int);
    int*    excl  = (int*)   (ws + off); off += (size_t)NNODES * sizeof(int);
    int*    cnt   = (int*)   (ws + off); off += (size_t)NNODES * sizeof(int);
    int*    bsums = (int*)   (ws + off); off += 512 * sizeof(int);
    int2*   dstsrc= (int2*)  (ws + off); off += (size_t)NEDGES * sizeof(int2);
    off = (off + 15) & ~(size_t)15;
    float4* eas   = (float4*)(ws + off); off += (size_t)NEDGES * sizeof(float4);
    ushort* w1p   = (ushort*)(ws + off); off += 32768 * sizeof(ushort);
    ushort* w2p   = (ushort*)(ws + off); off += 16384 * sizeof(ushort);

    zero_kernel<<<2048, 256, 0, stream>>>(out, hist, cnt, W1, W2, w1p, w2p);
    node_gemm1<<<G1_BLOCKS, 256, 0, stream>>>(x, w1p, b1, xab);
    hist_kernel<<<(NEDGES + 255) / 256, 256, 0, stream>>>(ei, hist);
    scan1_kernel<<<NSCAN_BLOCKS, 256, 0, stream>>>(hist, excl, bsums);
    scan2_kernel<<<1, 512, 0, stream>>>(bsums);
    scatter_kernel<<<(NEDGES + 255) / 256, 256, 0, stream>>>(ei, ea, excl, bsums, cnt,
                                                             dstsrc, eas);
    edge_silu_kernel<<<EDGE_BLOCKS, 512, 0, stream>>>(xab, dstsrc, eas,
                                                      W1, gamma, beta, out);
    node_gemm2<<<G1_BLOCKS, 256, 0, stream>>>(out, w2p, b2, hist);
}

// Round 14
// 191.512 us; speedup vs baseline: 1.0988x; 1.0988x over previous
//
#include <hip/hip_runtime.h>
#include <hip/hip_bf16.h>

#define NNODES 100000
#define NEDGES 640000
#define DIM 128
#define GS 16
#define EB 64                                  // edges per block (1 per thread, 256 thr)
#define NSCAN_BLOCKS ((NNODES + 255) / 256)    // 391
#define G1_BLOCKS ((NNODES + 63) / 64)         // 1563 (tail block: 32 rows)

typedef __attribute__((ext_vector_type(8))) short short8;
typedef __attribute__((ext_vector_type(4))) float f32x4;
typedef __attribute__((ext_vector_type(2))) float f2;
typedef __attribute__((ext_vector_type(4))) unsigned int uint4v;

__device__ __forceinline__ ushort f2bf(float f) {
    __hip_bfloat16 h = __float2bfloat16(f);
    return *reinterpret_cast<ushort*>(&h);
}
__device__ __forceinline__ float bf2f(ushort u) {
    union { unsigned int i; float f; } v; v.i = ((unsigned int)u) << 16; return v.f;
}
__device__ __forceinline__ f2 sp(float x) { return (f2){x, x}; }

// ---------------------------------------------------------------- zero init + weight pack
__global__ void zero_kernel(float* __restrict__ out, int* __restrict__ hist,
                            int* __restrict__ cnt,
                            const float* __restrict__ W1, const float* __restrict__ W2,
                            ushort* __restrict__ w1p, ushort* __restrict__ w2p) {
    long step = (long)gridDim.x * blockDim.x;
    long i0 = (long)blockIdx.x * blockDim.x + threadIdx.x;
    const long total = (long)NNODES * DIM;
    for (long i = i0; i < total; i += step) out[i] = 0.f;
    for (long i = i0; i < NNODES; i += step) { hist[i] = 0; cnt[i] = 0; }
    int idx = (int)i0;
    if (idx < 32768) {
        int j    = idx & 7;
        int lane = (idx >> 3) & 63;
        int kt   = (idx >> 9) & 3;
        int nt   = (idx >> 11) & 3;
        int w    = (idx >> 13) & 3;
        int lr = lane & 15, lg = lane >> 4;
        int koff = (w >= 2) ? 128 : 0;
        int cc = (w & 1) * 64 + nt * 16 + lr;
        int kb = koff + kt * 32 + lg * 8;
        w1p[idx] = f2bf(W1[(long)(kb + j) * DIM + cc]);
    } else if (idx < 49152) {
        int i2 = idx - 32768;   // < 16384
        int j    = i2 & 7;
        int lane = (i2 >> 3) & 63;
        int kt   = (i2 >> 9) & 3;
        int nt   = (i2 >> 11) & 1;
        int w    = (i2 >> 12) & 3;
        int lr = lane & 15, lg = lane >> 4;
        int cc = w * 32 + nt * 16 + lr;
        int kb = kt * 32 + lg * 8;
        w2p[i2] = f2bf(W2[(long)(kb + j) * DIM + cc]);
    }
}

// ---------------------------------------------------------------- node GEMM1 (MFMA)
// xab[n][0:128] = x@W1a + b1 (b1 folded),  xab[n][128:256] = x@W1b   (bf16)
__global__ __launch_bounds__(256) void node_gemm1(const float* __restrict__ x,
                                                  const ushort* __restrict__ w1p,
                                                  const float* __restrict__ b1,
                                                  ushort* __restrict__ xab) {
    __shared__ __align__(16) char xt[64 * 256];   // 64 rows x 128 bf16, XOR-swizzled
    const int tid  = threadIdx.x;
    const int lane = tid & 63;
    const int w    = tid >> 6;
    const int lr   = lane & 15;
    const int lg   = lane >> 4;
    const int m0   = blockIdx.x * 64;
    const int mtMax = (m0 + 64 <= NNODES) ? 4 : 2;
    const int koff = (w >= 2) ? 128 : 0;

    short8 bfrag[4][4];
    #pragma unroll
    for (int nt = 0; nt < 4; ++nt)
        #pragma unroll
        for (int kt = 0; kt < 4; ++kt)
            bfrag[nt][kt] = *(const short8*)&w1p[(((w * 4 + nt) * 4 + kt) << 9) + lane * 8];

    {
        const int r  = tid >> 2;
        const int kq = (tid & 3) * 32;
        if (m0 + r < NNODES) {
            const float* xr = &x[(long)(m0 + r) * DIM + kq];
            ushort tmp[32];
            #pragma unroll
            for (int j = 0; j < 32; ++j) tmp[j] = f2bf(xr[j]);
            #pragma unroll
            for (int i = 0; i < 4; ++i) {
                int byte = r * 256 + kq * 2 + i * 16;
                byte ^= (r & 7) << 4;
                *(short8*)(xt + byte) = *(short8*)&tmp[i * 8];
            }
        }
    }
    __syncthreads();

    const int colBase = w * 64;
    for (int mt = 0; mt < mtMax; ++mt) {
        short8 afrag[4];
        #pragma unroll
        for (int kt = 0; kt < 4; ++kt) {
            const int row = mt * 16 + lr;
            int byte = row * 256 + (kt * 4 + lg) * 16;
            byte ^= (row & 7) << 4;
            afrag[kt] = *(short8*)(xt + byte);
        }
        f32x4 acc[4] = {};
        #pragma unroll
        for (int nt = 0; nt < 4; ++nt)
            #pragma unroll
            for (int kt = 0; kt < 4; ++kt)
                acc[nt] = __builtin_amdgcn_mfma_f32_16x16x32_bf16(afrag[kt], bfrag[nt][kt], acc[nt], 0, 0, 0);
        #pragma unroll
        for (int nt = 0; nt < 4; ++nt) {
            const int col = colBase + nt * 16 + lr;
            const float badd = (koff == 0) ? b1[col] : 0.f;
            #pragma unroll
            for (int r = 0; r < 4; ++r) {
                const int row = m0 + mt * 16 + lg * 4 + r;
                xab[(long)row * 256 + col] = f2bf(acc[nt][r] + badd);
            }
        }
    }
}

// ---------------------------------------------------------------- histogram
__global__ void hist_kernel(const int* __restrict__ ei, int* __restrict__ hist) {
    int e = blockIdx.x * 256 + threadIdx.x;
    if (e < NEDGES) atomicAdd(&hist[ei[NEDGES + e]], 1);
}

// ---------------------------------------------------------------- 2-level scan
__global__ void scan1_kernel(const int* __restrict__ hist, int* __restrict__ excl,
                             int* __restrict__ bsums) {
    __shared__ int s[256];
    int tid = threadIdx.x;
    int i = blockIdx.x * 256 + tid;
    int v = (i < NNODES) ? hist[i] : 0;
    s[tid] = v;
    __syncthreads();
    for (int o = 1; o < 256; o <<= 1) {
        int t = (tid >= o) ? s[tid - o] : 0;
        __syncthreads();
        s[tid] += t;
        __syncthreads();
    }
    if (i < NNODES) excl[i] = s[tid] - v;
    if (tid == 255) bsums[blockIdx.x] = s[255];
}

__global__ void scan2_kernel(int* __restrict__ bsums) {
    __shared__ int s[512];
    int tid = threadIdx.x;
    int v = (tid < NSCAN_BLOCKS) ? bsums[tid] : 0;
    s[tid] = v;
    __syncthreads();
    for (int o = 1; o < 512; o <<= 1) {
        int t = (tid >= o) ? s[tid - o] : 0;
        __syncthreads();
        s[tid] += t;
        __syncthreads();
    }
    if (tid < NSCAN_BLOCKS) bsums[tid] = s[tid] - v;   // exclusive
}

// ---------------------------------------------------------------- scatter (counting sort)
__global__ void scatter_kernel(const int* __restrict__ ei, const float* __restrict__ ea,
                               const int* __restrict__ excl, const int* __restrict__ bsums,
                               int* __restrict__ cnt,
                               int2* __restrict__ dstsrc, float4* __restrict__ eas) {
    int e = blockIdx.x * 256 + threadIdx.x;
    if (e < NEDGES) {
        int d = ei[NEDGES + e];
        int pos = excl[d] + bsums[d >> 8] + atomicAdd(&cnt[d], 1);
        dstsrc[pos] = make_int2(d, ei[e]);
        eas[pos] = *(const float4*)&ea[(long)e * 4];
    }
}

// ---------------------------------------------------------------- edge phase
// r12-proven geometry: 256 thr, 64 edges/block; pair-packed math;
// bf16 swizzled LDS; 2x32-edge segmented walk -> merged atomics
__global__ __launch_bounds__(256) void edge_silu_kernel(
    const ushort* __restrict__ xab,
    const int2* __restrict__ dstsrc, const float4* __restrict__ eas,
    const float* __restrict__ W1,
    const float* __restrict__ gamma, const float* __restrict__ beta,
    float* __restrict__ out)
{
    __shared__ __align__(16) ushort ssilu[EB * 128];   // 16 KB bf16, XOR-swizzled rows
    __shared__ __align__(16) float4 wA[68];            // skew p = pi + (pi>>4)
    __shared__ __align__(16) float4 wB[68];
    __shared__ __align__(16) float4 gbp[68];
    __shared__ int2   sds[EB];
    __shared__ float4 sea4[EB];

    const int tid = threadIdx.x;
    const int e0 = blockIdx.x * EB;

    if (tid < EB) {
        sds[tid]  = dstsrc[e0 + tid];
        sea4[tid] = eas[e0 + tid];
        if (tid < 64) {
            int pi = tid;
            int c0 = 2 * pi;
            int p = pi + (pi >> 4);
            wA[p]  = make_float4(W1[256 * DIM + c0], W1[256 * DIM + c0 + 1],
                                 W1[257 * DIM + c0], W1[257 * DIM + c0 + 1]);
            wB[p]  = make_float4(W1[258 * DIM + c0], W1[258 * DIM + c0 + 1],
                                 W1[259 * DIM + c0], W1[259 * DIM + c0 + 1]);
            gbp[p] = make_float4(gamma[c0], gamma[c0 + 1], beta[c0], beta[c0 + 1]);
        }
    }
    __syncthreads();

    // h-phase: thread owns edge e = tid>>2, channel pairs [q*16, q*16+16)
    {
        const int e = tid >> 2;
        const int q = tid & 3;
        const int c0 = q * 32;
        const int2 ds = sds[e];
        const uint* xaRow = (const uint*)&xab[(long)ds.x * 256 + c0];
        const uint* xbRow = (const uint*)&xab[(long)ds.y * 256 + 128 + c0];
        const float4 a = sea4[e];

        uint4v ua[4], ub[4];
        #pragma unroll
        for (int i = 0; i < 4; ++i) {
            ua[i] = *(const uint4v*)&xaRow[i * 4];
            ub[i] = *(const uint4v*)&xbRow[i * 4];
        }

        f2 v2[16];
        #pragma unroll
        for (int k = 0; k < 16; ++k) {
            const int p = q * 16 + k + q;                 // skewed pair index
            const float4 a01 = wA[p];
            const float4 a23 = wB[p];
            f2 acc = (f2){a01.x, a01.y} * sp(a.x) + (f2){a01.z, a01.w} * sp(a.y)
                   + (f2){a23.x, a23.y} * sp(a.z) + (f2){a23.z, a23.w} * sp(a.w);
            const uint uga = ua[k >> 2][k & 3];
            const uint ugb = ub[k >> 2][k & 3];
            acc += (f2){__uint_as_float(uga << 16), __uint_as_float(uga & 0xffff0000u)};
            acc += (f2){__uint_as_float(ugb << 16), __uint_as_float(ugb & 0xffff0000u)};
            v2[k] = acc;
        }

        // GroupNorm (one-pass) + SiLU; thread owns 2 groups = 8 pairs each
        #pragma unroll
        for (int g = 0; g < 2; ++g) {
            f2 s = sp(0.f), ss = sp(0.f);
            #pragma unroll
            for (int ip = 0; ip < 8; ++ip) {
                f2 a2 = v2[g * 8 + ip];
                s += a2; ss += a2 * a2;
            }
            const float sum = s.x + s.y;
            const float sq  = ss.x + ss.y;
            const float m = sum * (1.f / GS);
            const float var = sq * (1.f / GS) - m * m;
            const float inv = __builtin_amdgcn_rsqf(var + 1e-5f);
            #pragma unroll
            for (int ip = 0; ip < 8; ++ip) {
                const int k = g * 8 + ip;
                const int p = q * 16 + k + q;
                const float4 gb4 = gbp[p];
                f2 sc  = (f2){gb4.x, gb4.y} * sp(inv);
                f2 off = (f2){gb4.z, gb4.w} - sc * sp(m);
                f2 t = v2[k] * sc + off;
                f2 r;
                r.x = t.x * __builtin_amdgcn_rcpf(1.f + __expf(-t.x));
                r.y = t.y * __builtin_amdgcn_rcpf(1.f + __expf(-t.y));
                v2[k] = r;
            }
        }

        // store silu as bf16, proven row-XOR swizzle
        ushort tmp[32];
        #pragma unroll
        for (int k = 0; k < 16; ++k) { tmp[2 * k] = f2bf(v2[k].x); tmp[2 * k + 1] = f2bf(v2[k].y); }
        #pragma unroll
        for (int i = 0; i < 4; ++i) {
            int byte = (e * 256 + (c0 + i * 8) * 2) ^ ((e & 7) << 4);
            *(short8*)((char*)ssilu + byte) = *(short8*)&tmp[i * 8];
        }
    }
    __syncthreads();

    // segmented column-walk: thread = (channel c, half h of 32 edges); lane-uniform branch
    {
        const int c = tid & 127;
        const int h = tid >> 7;
        const int eS = h * 32, eE = eS + 32;
        float r = 0.f;
        int cur = sds[eS].x;
        for (int ee = eS; ee < eE; ++ee) {
            int d = sds[ee].x;
            if (d != cur) {
                unsafeAtomicAdd(&out[(long)cur * DIM + c], r);
                r = 0.f; cur = d;
            }
            int byte = (ee * 256 + c * 2) ^ ((ee & 7) << 4);
            r += bf2f(*(const ushort*)((const char*)ssilu + byte));
        }
        unsafeAtomicAdd(&out[(long)cur * DIM + c], r);
    }
}

// ---------------------------------------------------------------- node GEMM2 (MFMA, in-place)
__global__ __launch_bounds__(256) void node_gemm2(float* __restrict__ out,
                                                  const ushort* __restrict__ w2p,
                                                  const float* __restrict__ b2,
                                                  const int* __restrict__ hist) {
    __shared__ __align__(16) char at[64 * 256];
    __shared__ float sb2[128];
    __shared__ int scnt[64];
    const int tid  = threadIdx.x;
    const int lane = tid & 63;
    const int w    = tid >> 6;
    const int lr   = lane & 15;
    const int lg   = lane >> 4;
    const int m0   = blockIdx.x * 64;
    const int mtMax = (m0 + 64 <= NNODES) ? 4 : 2;

    short8 bfrag[2][4];
    #pragma unroll
    for (int nt = 0; nt < 2; ++nt)
        #pragma unroll
        for (int kt = 0; kt < 4; ++kt)
            bfrag[nt][kt] = *(const short8*)&w2p[(((w * 2 + nt) * 4 + kt) << 9) + lane * 8];

    if (tid < 128) sb2[tid] = b2[tid];
    if (tid < 64 && m0 + tid < NNODES) scnt[tid] = hist[m0 + tid];

    {
        const int r  = tid >> 2;
        const int kq = (tid & 3) * 32;
        if (m0 + r < NNODES) {
            const float* ar = &out[(long)(m0 + r) * DIM + kq];
            ushort tmp[32];
            #pragma unroll
            for (int j = 0; j < 32; ++j) tmp[j] = f2bf(ar[j]);
            #pragma unroll
            for (int i = 0; i < 4; ++i) {
                int byte = r * 256 + kq * 2 + i * 16;
                byte ^= (r & 7) << 4;
                *(short8*)(at + byte) = *(short8*)&tmp[i * 8];
            }
        }
    }
    __syncthreads();

    for (int mt = 0; mt < mtMax; ++mt) {
        short8 afrag[4];
        #pragma unroll
        for (int kt = 0; kt < 4; ++kt) {
            const int row = mt * 16 + lr;
            int byte = row * 256 + (kt * 4 + lg) * 16;
            byte ^= (row & 7) << 4;
            afrag[kt] = *(short8*)(at + byte);
        }
        f32x4 acc[2] = {};
        #pragma unroll
        for (int nt = 0; nt < 2; ++nt)
            #pragma unroll
            for (int kt = 0; kt < 4; ++kt)
                acc[nt] = __builtin_amdgcn_mfma_f32_16x16x32_bf16(afrag[kt], bfrag[nt][kt], acc[nt], 0, 0, 0);
        #pragma unroll
        for (int nt = 0; nt < 2; ++nt) {
            const int col = w * 32 + nt * 16 + lr;
            #pragma unroll
            for (int r = 0; r < 4; ++r) {
                const int rr = mt * 16 + lg * 4 + r;
                float cnt = (float)scnt[rr];
                float sc = __builtin_amdgcn_rcpf(fmaxf(cnt, 1.f));
                out[(long)(m0 + rr) * DIM + col] = (acc[nt][r] + cnt * sb2[col]) * sc;
            }
        }
    }
}

// ---------------------------------------------------------------- launch
extern "C" void kernel_launch(void* const* d_in, const int* in_sizes, int n_in,
                              void* d_out, int out_size, void* d_ws, size_t ws_size,
                              hipStream_t stream) {
    const float* x     = (const float*)d_in[0];
    const int*   ei    = (const int*)  d_in[1];
    const float* ea    = (const float*)d_in[2];
    const float* W1    = (const float*)d_in[3];
    const float* b1    = (const float*)d_in[4];
    const float* gamma = (const float*)d_in[5];
    const float* beta  = (const float*)d_in[6];
    const float* W2    = (const float*)d_in[7];
    const float* b2    = (const float*)d_in[8];
    float* out = (float*)d_out;

    char* ws = (char*)d_ws;
    size_t off = 0;
    ushort* xab   = (ushort*)(ws + off); off += (size_t)NNODES * 256 * sizeof(ushort);
    int*    hist  = (int*)   (ws + off); off += (size_t)NNODES * sizeof(int);
    int*    excl  = (int*)   (ws + off); off += (size_t)NNODES * sizeof(int);
    int*    cnt   = (int*)   (ws + off); off += (size_t)NNODES * sizeof(int);
    int*    bsums = (int*)   (ws + off); off += 512 * sizeof(int);
    int2*   dstsrc= (int2*)  (ws + off); off += (size_t)NEDGES * sizeof(int2);
    off = (off + 15) & ~(size_t)15;
    float4* eas   = (float4*)(ws + off); off += (size_t)NEDGES * sizeof(float4);
    ushort* w1p   = (ushort*)(ws + off); off += 32768 * sizeof(ushort);
    ushort* w2p   = (ushort*)(ws + off); off += 16384 * sizeof(ushort);

    zero_kernel<<<2048, 256, 0, stream>>>(out, hist, cnt, W1, W2, w1p, w2p);
    node_gemm1<<<G1_BLOCKS, 256, 0, stream>>>(x, w1p, b1, xab);
    hist_kernel<<<(NEDGES + 255) / 256, 256, 0, stream>>>(ei, hist);
    scan1_kernel<<<NSCAN_BLOCKS, 256, 0, stream>>>(hist, excl, bsums);
    scan2_kernel<<<1, 512, 0, stream>>>(bsums);
    scatter_kernel<<<(NEDGES + 255) / 256, 256, 0, stream>>>(ei, ea, excl, bsums, cnt,
                                                             dstsrc, eas);
    edge_silu_kernel<<<NEDGES / EB, 256, 0, stream>>>(xab, dstsrc, eas,
                                                      W1, gamma, beta, out);
    node_gemm2<<<G1_BLOCKS, 256, 0, stream>>>(out, w2p, b2, hist);
}